// Round 5
// baseline (14618.860 us; speedup 1.0000x reference)
//
#include <hip/hip_runtime.h>
#include <math.h>

// SA_Layer2 — ROUND 5: same naive structure as round 4 (which executed and is
// believed mathematically correct), with the SINGLE change: output is FP32.
// Forensics: round-3 NaN proves inputs are fp32 (bf16 misread hits exp=0xFF);
// round-4's 9.047 error exactly matches bf16-packed writes into an fp32-read
// buffer (odd-index value + zeroed tail). Inputs fp32, output fp32,
// intermediates bf16 (u16) in ws. No MFMA yet — establish green first.
//
// B=8, C=512, C4=128, H=1024, W=8, HW=8192. s = b*8+w (64 slices).
//   K1: Qs[s][h][d]  = sum_c qk_w[d,c] * x[b,c,h,w]                (bf16)
//   K2: lbuf[s][j]   = (1+1e-9) * sum_i exp(E[i,j]),  E = Q.Q^T    (fp32)
//   K3: Vt[s][i][c]  = sum_cc v_w[c,cc] * x[b,cc,i,w] + v_b[c]     (bf16)
//   K4: XR[b][c][hw] = sum_i Vt[s][i][c] * exp(E[i,j]) / lbuf      (bf16)
//   K5: d_out(T)     = sum_c t_w[o,c] * (x - XR) + t_b[o]          (fp32)
//   K6: bnp: BN scale/shift per channel (biased var, eps 1e-5)
//   K7: out = x + relu(T*scale + shift)   (in place on d_out, fp32)

typedef unsigned short u16;

__device__ __forceinline__ float b2f(u16 u) {
    unsigned x = ((unsigned)u) << 16;
    float f;
    __builtin_memcpy(&f, &x, 4);
    return f;
}
__device__ __forceinline__ u16 f2b(float f) {
    unsigned x;
    __builtin_memcpy(&x, &f, 4);
    unsigned r = (x + 0x7fffu + ((x >> 16) & 1u)) >> 16;  // round-nearest-even
    return (u16)r;
}
// clamped exp: correctness-neutral for sane E (max ~45), prevents inf->NaN
__device__ __forceinline__ float expc(float e) {
    return expf(fminf(e, 80.0f));
}

// K1: thread = (b, d, hw). Qs[s][h][d] bf16.
__global__ __launch_bounds__(256) void k1_qproj(
    const float* qk_w, const float* x, u16* Qs)
{
    const int n  = blockIdx.x * 256 + threadIdx.x;   // 2^23
    const int hw = n & 8191;
    const int d  = (n >> 13) & 127;
    const int b  = n >> 20;
    float acc = 0.f;
    for (int c = 0; c < 512; ++c)
        acc += qk_w[d * 512 + c] * x[((long)(b * 512 + c)) * 8192 + hw];
    const int h = hw >> 3, w = hw & 7;
    Qs[((long)((b * 8 + w) * 1024 + h)) * 128 + d] = f2b(acc);
}

// K2: block = 4 waves; wave = (s, j). Lane-serial dot over d, LDS reduce.
__global__ __launch_bounds__(256) void k2_lsum(
    const u16* Qs, float* lbuf)
{
    const int tid  = threadIdx.x;
    const int wv   = tid >> 6;
    const int lane = tid & 63;
    const int gw   = blockIdx.x * 4 + wv;     // 0..65535
    const int s    = gw >> 10;
    const int j    = gw & 1023;
    const u16* q = Qs + (long)s * 1024 * 128;

    float sum = 0.f;
    for (int i = lane; i < 1024; i += 64) {
        float e = 0.f;
        for (int d = 0; d < 128; ++d)
            e += b2f(q[i * 128 + d]) * b2f(q[j * 128 + d]);
        sum += expc(e);
    }
    __shared__ float red[256];
    red[tid] = sum;
    __syncthreads();
    for (int o = 32; o > 0; o >>= 1) {
        if (lane < o) red[tid] += red[tid + o];
        __syncthreads();
    }
    if (lane == 0)
        lbuf[s * 1024 + j] = red[wv * 64] * (1.0f + 1e-9f);
}

// K3: thread = (b, c, hw). Vt[s][i=h][c] bf16 (c contiguous for K4).
__global__ __launch_bounds__(256) void k3_vproj(
    const float* v_w, const float* v_b, const float* x, u16* Vt)
{
    const int n  = blockIdx.x * 256 + threadIdx.x;   // 2^25
    const int hw = n & 8191;
    const int c  = (n >> 13) & 511;
    const int b  = n >> 22;
    float acc = v_b[c];
    for (int cc = 0; cc < 512; ++cc)
        acc += v_w[c * 512 + cc] * x[((long)(b * 512 + cc)) * 8192 + hw];
    const int h = hw >> 3, w = hw & 7;
    Vt[((long)((b * 8 + w) * 1024 + h)) * 512 + c] = f2b(acc);
}

// K4: block = (jt, s); j-tile 16, all 512 c, i in tiles of 64.
__global__ __launch_bounds__(256) void k4_xr(
    const u16* Qs, const u16* Vt, const float* lbuf, u16* XR)
{
    const int tid = threadIdx.x;
    const int jt  = blockIdx.x;        // 0..63
    const int s   = blockIdx.y;        // 0..63
    const int b   = s >> 3, w = s & 7;
    const int j0  = jt * 16;
    const u16* q = Qs + (long)s * 1024 * 128;
    const u16* v = Vt + (long)s * 1024 * 512;

    __shared__ u16   qj[16][128];
    __shared__ float att[64][17];
    __shared__ float rls[16];

    for (int idx = tid; idx < 16 * 128; idx += 256)
        qj[idx >> 7][idx & 127] = q[(j0 + (idx >> 7)) * 128 + (idx & 127)];
    if (tid < 16)
        rls[tid] = 1.0f / lbuf[s * 1024 + j0 + tid];

    const int ii = tid & 63;       // E-phase row
    const int jg = tid >> 6;       // E-phase j-group (4 j each)
    const int c0 = tid;            // MAC-phase channels
    const int c1 = tid + 256;

    float accA[16], accB[16];
    for (int j = 0; j < 16; ++j) { accA[j] = 0.f; accB[j] = 0.f; }

    for (int it = 0; it < 16; ++it) {
        const int i0 = it * 64;
        __syncthreads();   // staging done (it==0) / previous MAC reads done
        float e[4];
        e[0] = e[1] = e[2] = e[3] = 0.f;
        for (int d = 0; d < 128; ++d) {
            const float qv = b2f(q[(i0 + ii) * 128 + d]);
            for (int jj = 0; jj < 4; ++jj)
                e[jj] += qv * b2f(qj[jg * 4 + jj][d]);
        }
        for (int jj = 0; jj < 4; ++jj) {
            const int j = jg * 4 + jj;
            att[ii][j] = expc(e[jj]) * rls[j];
        }
        __syncthreads();
        for (int i2 = 0; i2 < 64; ++i2) {
            const float va = b2f(v[(i0 + i2) * 512 + c0]);
            const float vb = b2f(v[(i0 + i2) * 512 + c1]);
            for (int j = 0; j < 16; ++j) {
                const float a = att[i2][j];
                accA[j] += va * a;
                accB[j] += vb * a;
            }
        }
    }
    for (int j = 0; j < 16; ++j) {
        XR[((long)(b * 512 + c0)) * 8192 + (j0 + j) * 8 + w] = f2b(accA[j]);
        XR[((long)(b * 512 + c1)) * 8192 + (j0 + j) * 8 + w] = f2b(accB[j]);
    }
}

// K5: thread = (b, o, hw). T into d_out (FP32), x-layout.
__global__ __launch_bounds__(256) void k5_tproj(
    const float* t_w, const float* t_b, const float* x, const u16* XR, float* T)
{
    const int n  = blockIdx.x * 256 + threadIdx.x;
    const int hw = n & 8191;
    const int o  = (n >> 13) & 511;
    const int b  = n >> 22;
    float acc = t_b[o];
    for (int c = 0; c < 512; ++c) {
        const long idx = ((long)(b * 512 + c)) * 8192 + hw;
        acc += t_w[o * 512 + c] * (x[idx] - b2f(XR[idx]));
    }
    T[((long)(b * 512 + o)) * 8192 + hw] = acc;
}

// K6: one block per channel; deterministic LDS reduction; biased variance.
__global__ __launch_bounds__(256) void k6_bnstats(
    const float* T, const float* gamma, const float* beta, float* bnp)
{
    const int c   = blockIdx.x;
    const int tid = threadIdx.x;
    float s1 = 0.f, s2 = 0.f;
    for (int b = 0; b < 8; ++b) {
        const float* p = T + ((long)(b * 512 + c)) * 8192;
        for (int m = 0; m < 32; ++m) {
            const float f = p[m * 256 + tid];
            s1 += f;
            s2 += f * f;
        }
    }
    __shared__ float r1[256], r2[256];
    r1[tid] = s1; r2[tid] = s2;
    __syncthreads();
    for (int o = 128; o > 0; o >>= 1) {
        if (tid < o) { r1[tid] += r1[tid + o]; r2[tid] += r2[tid + o]; }
        __syncthreads();
    }
    if (tid == 0) {
        const float inv_n = 1.0f / 65536.0f;
        const float mean = r1[0] * inv_n;
        const float var  = r2[0] * inv_n - mean * mean;
        const float sc   = gamma[c] * rsqrtf(var + 1e-5f);
        bnp[c]       = sc;
        bnp[512 + c] = beta[c] - mean * sc;
    }
}

// K7: out = x + relu(T*scale + shift), in place on d_out (fp32).
__global__ __launch_bounds__(256) void k7_final(
    const float* x, const float* bnp, float* out)
{
    const long i = (long)blockIdx.x * 256 + threadIdx.x;   // 2^25 threads
    const int c = (int)((i >> 13) & 511);
    float t = out[i] * bnp[c] + bnp[512 + c];
    if (t < 0.f) t = 0.f;
    out[i] = x[i] + t;
}

extern "C" void kernel_launch(void* const* d_in, const int* in_sizes, int n_in,
                              void* d_out, int out_size, void* d_ws, size_t ws_size,
                              hipStream_t stream)
{
    const float* x     = (const float*)d_in[0];
    const float* qk_w  = (const float*)d_in[1];
    const float* v_w   = (const float*)d_in[2];
    const float* v_b   = (const float*)d_in[3];
    const float* t_w   = (const float*)d_in[4];
    const float* t_b   = (const float*)d_in[5];
    const float* gamma = (const float*)d_in[6];
    const float* beta  = (const float*)d_in[7];
    float* out = (float*)d_out;

    char* ws = (char*)d_ws;
    u16*   Qs   = (u16*)(ws);                    // 16 MiB  [64][1024][128]
    u16*   Vt   = (u16*)(ws + 16777216);         // 64 MiB  [64][1024][512]
    u16*   XR   = (u16*)(ws + 83886080);         // 64 MiB  x-layout
    float* lbuf = (float*)(ws + 150994944);      // 256 KiB [64][1024]
    float* bnp  = (float*)(ws + 151257088);      // 4 KiB
    // total ws use: 151,261,184 B (~144.3 MiB)

    k1_qproj <<<dim3(8 * 128 * 8192 / 256), 256, 0, stream>>>(qk_w, x, Qs);
    k2_lsum  <<<dim3(64 * 1024 / 4),        256, 0, stream>>>(Qs, lbuf);
    k3_vproj <<<dim3(8 * 512 * 8192 / 256), 256, 0, stream>>>(v_w, v_b, x, Vt);
    k4_xr    <<<dim3(64, 64),               256, 0, stream>>>(Qs, Vt, lbuf, XR);
    k5_tproj <<<dim3(8 * 512 * 8192 / 256), 256, 0, stream>>>(t_w, t_b, x, XR, out);
    k6_bnstats <<<dim3(512),                256, 0, stream>>>(out, gamma, beta, bnp);
    k7_final <<<dim3(33554432 / 256),       256, 0, stream>>>(x, bnp, out);
}